// Round 4
// baseline (258.247 us; speedup 1.0000x reference)
//
#include <hip/hip_runtime.h>
#include <stdint.h>

// Problem constants (match reference)
#define N_PRIORS 2097152
#define KTOP 512
#define NBINS 2048
#define NBLK 1024
#define RCAP 256                 // candidate slots per region (mean 123, sigma ~11)
#define ELEM_PER_BLK (N_PRIORS / NBLK)   // 2048
#define GBIN 1843                // bin_of(0.99): static stash pre-filter guess
#define STASH_CAP 2048
#define SELCAP 2048

// ws layout: [0,4K) u32 blk_cnt[1024]; [4K, 4K+2MB) u64 cand[NBLK*RCAP]

__device__ __forceinline__ uint64_t pack_key(float s, int idx) {
    // descending score, ascending index tie-break (== stable top_k)
    return ((uint64_t)__float_as_uint(s) << 32) | (uint32_t)(~idx);
}

__device__ __forceinline__ float score_of(float c0, float c1) {
    #pragma clang fp contract(off)
    float m  = fmaxf(c0, c1);
    float e0 = expf(c0 - m);
    float e1 = expf(c1 - m);
    return e1 / (e0 + e1);
}

__device__ __forceinline__ int bin_of(float s) {
    #pragma clang fp contract(off)
    int b = (int)((s - 0.9f) * 20480.0f);   // 2048 bins over (0.9, 1.0]
    return b > (NBINS - 1) ? (NBINS - 1) : b;
}

// K1: stream conf once; compact >0.9 candidates into fixed per-block regions.
// No same-address GLOBAL atomics anywhere (LDS counter only).
__global__ void k1_compact(const float4* __restrict__ conf4,
                           uint32_t* __restrict__ blk_cnt,
                           uint64_t* __restrict__ cand) {
    #pragma clang fp contract(off)
    __shared__ uint32_t lcnt;
    int t = threadIdx.x;            // 256 threads
    int blk = blockIdx.x;           // 1024 blocks, 2048 elements each
    if (t == 0) lcnt = 0;
    __syncthreads();
    int base4 = blk * (ELEM_PER_BLK / 2);   // float4 index base (2 elems per float4)
    uint64_t* reg = cand + (size_t)blk * RCAP;
    #pragma unroll
    for (int i = 0; i < 4; ++i) {
        int f4i = base4 + t + 256 * i;
        float4 c = conf4[f4i];
        float s0 = score_of(c.x, c.y);
        float s1 = score_of(c.z, c.w);
        if (s0 > 0.9f) {
            uint32_t p = atomicAdd(&lcnt, 1u);
            if (p < RCAP) reg[p] = pack_key(s0, f4i * 2);
        }
        if (s1 > 0.9f) {
            uint32_t p = atomicAdd(&lcnt, 1u);
            if (p < RCAP) reg[p] = pack_key(s1, f4i * 2 + 1);
        }
    }
    __syncthreads();
    if (t == 0) blk_cnt[blk] = lcnt < RCAP ? lcnt : RCAP;
}

// K2: single block does everything else: LDS histogram -> threshold bin B ->
// select -> bitonic sort -> decode -> suppression matrix (named regs, no
// local arrays => no scratch spill) -> greedy bitmask scan -> output.
__launch_bounds__(1024)
__global__ void k2_finish(const float4* __restrict__ loc,
                          const float4* __restrict__ priors,
                          const uint32_t* __restrict__ blk_cnt,
                          const uint64_t* __restrict__ cand,
                          float* __restrict__ out) {
    #pragma clang fp contract(off)
    __shared__ uint64_t arena[STASH_CAP + SELCAP];  // 32 KB
    uint64_t* stash = arena;                        // dead after selection
    uint64_t* sel   = arena + STASH_CAP;            // sorted keys; dead after decode
    uint8_t*  supB  = (uint8_t*)arena;              // 32 KB alias, used after decode
    __shared__ uint32_t hist[NBINS];                // 8 KB; becomes suffix counts
    __shared__ float4 bpk[KTOP];                    // 8 KB pixel boxes
    __shared__ float  sar[KTOP], ssc[KTOP];         // 4 KB
    __shared__ uint32_t valid32[16], rowany32[16];
    __shared__ uint64_t keepw[8];
    __shared__ uint32_t nstashS, nselS;
    __shared__ int bmaxS;

    int tid = threadIdx.x;          // 1024 threads
    int lane = tid & 63, wv = tid >> 6;

    // ---- init ----
    for (int b = tid; b < NBINS; b += 1024) hist[b] = 0u;
    if (tid < 16) { valid32[tid] = 0u; rowany32[tid] = 0u; }
    if (tid == 0) { nstashS = 0u; nselS = 0u; bmaxS = 0; }
    __syncthreads();

    // ---- stream candidates once: LDS histogram + LDS stash (bin >= GBIN) ----
    for (int r = wv; r < NBLK; r += 16) {
        uint32_t c = blk_cnt[r];
        const uint64_t* regp = cand + (size_t)r * RCAP;
        for (uint32_t base = 0; base < c; base += 128) {
            uint32_t e0 = base + 2 * lane, e1 = e0 + 1;
            uint64_t ka = 0ull, kb = 0ull;
            if (e1 < c) {
                ulonglong2 v = ((const ulonglong2*)regp)[(base >> 1) + lane];
                ka = v.x; kb = v.y;
            } else if (e0 < c) {
                ka = regp[e0];
            }
            if (ka) {
                int b = bin_of(__uint_as_float((uint32_t)(ka >> 32)));
                atomicAdd(&hist[b], 1u);
                if (b >= GBIN) {
                    uint32_t p = atomicAdd(&nstashS, 1u);
                    if (p < STASH_CAP) stash[p] = ka;
                }
            }
            if (kb) {
                int b = bin_of(__uint_as_float((uint32_t)(kb >> 32)));
                atomicAdd(&hist[b], 1u);
                if (b >= GBIN) {
                    uint32_t p = atomicAdd(&nstashS, 1u);
                    if (p < STASH_CAP) stash[p] = kb;
                }
            }
        }
    }
    __syncthreads();

    // ---- suffix scan of hist (in place), find B ----
    for (int off = 1; off < NBINS; off <<= 1) {
        int b0 = tid, b1 = tid + 1024;
        uint32_t v0 = hist[b0] + ((b0 + off < NBINS) ? hist[b0 + off] : 0u);
        uint32_t v1 = hist[b1] + ((b1 + off < NBINS) ? hist[b1 + off] : 0u);
        __syncthreads();
        hist[b0] = v0; hist[b1] = v1;
        __syncthreads();
    }
    if (hist[tid] >= KTOP) atomicMax(&bmaxS, tid);
    if (hist[tid + 1024] >= KTOP) atomicMax(&bmaxS, tid + 1024);
    __syncthreads();
    int B = bmaxS;
    bool stash_ok = (hist[GBIN] >= KTOP) && (nstashS <= STASH_CAP);
    __syncthreads();

    // ---- selection: bin >= B -> sel ----
    if (stash_ok) {
        uint32_t ns = nstashS < STASH_CAP ? nstashS : STASH_CAP;
        for (uint32_t t = tid; t < ns; t += 1024) {
            uint64_t k = stash[t];
            if (bin_of(__uint_as_float((uint32_t)(k >> 32))) >= B) {
                uint32_t p = atomicAdd(&nselS, 1u);
                if (p < SELCAP) sel[p] = k;
            }
        }
    } else {
        // correct general path: re-read regions (cold path, normally never taken)
        for (int r = wv; r < NBLK; r += 16) {
            uint32_t c = blk_cnt[r];
            const uint64_t* regp = cand + (size_t)r * RCAP;
            for (uint32_t e = lane; e < c; e += 64) {
                uint64_t k = regp[e];
                if (bin_of(__uint_as_float((uint32_t)(k >> 32))) >= B) {
                    uint32_t p = atomicAdd(&nselS, 1u);
                    if (p < SELCAP) sel[p] = k;
                }
            }
        }
    }
    __syncthreads();

    int n = (int)nselS; if (n > SELCAP) n = SELCAP;
    int P = 1024; while (P < n) P <<= 1;
    for (int t = tid; t < P; t += 1024) if (t >= n) sel[t] = 0ull;
    __syncthreads();

    // ---- bitonic sort, descending (0-padding sinks) ----
    for (int k = 2; k <= P; k <<= 1) {
        for (int j = k >> 1; j > 0; j >>= 1) {
            for (int t = tid; t < P; t += 1024) {
                int ixj = t ^ j;
                if (ixj > t) {
                    uint64_t a = sel[t], b = sel[ixj];
                    bool sw = ((t & k) == 0) ? (a < b) : (a > b);
                    if (sw) { sel[t] = b; sel[ixj] = a; }
                }
            }
            __syncthreads();
        }
    }

    // ---- decode top-512 (exact numpy op order) ----
    if (tid < KTOP) {
        uint64_t key = sel[tid];
        float4 bb; float area, sc;
        if (key != 0ull) {
            sc = __uint_as_float((uint32_t)(key >> 32));
            int idx  = (int)(~(uint32_t)key);
            float4 l = loc[idx];
            float4 p = priors[idx];
            float cx = p.x + (l.x * 0.1f) * p.z;
            float cy = p.y + (l.y * 0.1f) * p.w;
            float w  = p.z * expf(l.z * 0.2f);
            float h  = p.w * expf(l.w * 0.2f);
            float x1 = cx - w * 0.5f;
            float y1 = cy - h * 0.5f;
            float x2 = x1 + w;
            float y2 = y1 + h;
            x1 *= 2048.0f; y1 *= 2048.0f; x2 *= 2048.0f; y2 *= 2048.0f;
            bb = make_float4(x1, y1, x2, y2);
            area = (x2 - x1 + 1.0f) * (y2 - y1 + 1.0f);
            atomicOr(&valid32[tid >> 5], 1u << (tid & 31));
        } else {
            bb = make_float4(0.f, 0.f, 0.f, 0.f); area = 1.f; sc = 0.f;
        }
        bpk[tid] = bb; sar[tid] = area; ssc[tid] = sc;
    }
    __syncthreads();   // sel dead; supB (aliasing arena) live from here

    // ---- suppression matrix: named registers only (no spillable arrays) ----
    {
        float4 cb0 = bpk[lane * 8 + 0], cb1 = bpk[lane * 8 + 1];
        float4 cb2 = bpk[lane * 8 + 2], cb3 = bpk[lane * 8 + 3];
        float4 cb4 = bpk[lane * 8 + 4], cb5 = bpk[lane * 8 + 5];
        float4 cb6 = bpk[lane * 8 + 6], cb7 = bpk[lane * 8 + 7];
        // identical formula+inputs as decode -> bit-identical areas
        float ca0 = (cb0.z - cb0.x + 1.0f) * (cb0.w - cb0.y + 1.0f);
        float ca1 = (cb1.z - cb1.x + 1.0f) * (cb1.w - cb1.y + 1.0f);
        float ca2 = (cb2.z - cb2.x + 1.0f) * (cb2.w - cb2.y + 1.0f);
        float ca3 = (cb3.z - cb3.x + 1.0f) * (cb3.w - cb3.y + 1.0f);
        float ca4 = (cb4.z - cb4.x + 1.0f) * (cb4.w - cb4.y + 1.0f);
        float ca5 = (cb5.z - cb5.x + 1.0f) * (cb5.w - cb5.y + 1.0f);
        float ca6 = (cb6.z - cb6.x + 1.0f) * (cb6.w - cb6.y + 1.0f);
        float ca7 = (cb7.z - cb7.x + 1.0f) * (cb7.w - cb7.y + 1.0f);
        #define IOUC(c, CB, CA) do { \
            float xx1 = fmaxf(rb.x, CB.x); float yy1 = fmaxf(rb.y, CB.y); \
            float xx2 = fminf(rb.z, CB.z); float yy2 = fminf(rb.w, CB.w); \
            float ww = fmaxf(xx2 - xx1 + 1.0f, 0.0f); \
            float hh = fmaxf(yy2 - yy1 + 1.0f, 0.0f); \
            float inter = ww * hh; \
            float iou = inter / (ra + (CA) - inter); \
            if (iou > 0.4f && (lane * 8 + (c)) > r) m8 |= (1u << (c)); } while (0)
        for (int rr = 0; rr < 32; ++rr) {
            int r = wv * 32 + rr;
            float4 rb = bpk[r];     // wave-uniform broadcast
            float ra = sar[r];
            uint32_t m8 = 0u;
            IOUC(0, cb0, ca0); IOUC(1, cb1, ca1); IOUC(2, cb2, ca2); IOUC(3, cb3, ca3);
            IOUC(4, cb4, ca4); IOUC(5, cb5, ca5); IOUC(6, cb6, ca6); IOUC(7, cb7, ca7);
            supB[r * 64 + lane] = (uint8_t)m8;
            if (m8) atomicOr(&rowany32[r >> 5], 1u << (r & 31));
        }
        #undef IOUC
    }
    __syncthreads();

    // ---- greedy scan: one thread, bitmask registers, O(#suppressing rows) ----
    if (tid == 0) {
        const uint64_t* sup64 = (const uint64_t*)supB;
        #define VA64(c) (((uint64_t)valid32[2*(c)]) | (((uint64_t)valid32[2*(c)+1]) << 32))
        #define RA64(c) (((uint64_t)rowany32[2*(c)]) | (((uint64_t)rowany32[2*(c)+1]) << 32))
        uint64_t kp0 = VA64(0), kp1 = VA64(1), kp2 = VA64(2), kp3 = VA64(3);
        uint64_t kp4 = VA64(4), kp5 = VA64(5), kp6 = VA64(6), kp7 = VA64(7);
        #define APPLYROW(i) do { const uint64_t* rp = sup64 + (size_t)(i) * 8; \
            kp0 &= ~rp[0]; kp1 &= ~rp[1]; kp2 &= ~rp[2]; kp3 &= ~rp[3]; \
            kp4 &= ~rp[4]; kp5 &= ~rp[5]; kp6 &= ~rp[6]; kp7 &= ~rp[7]; } while (0)
        #define CHUNK(c, KPC) do { uint64_t ra = RA64(c); uint64_t m = (KPC) & ra; \
            while (m) { int b = __builtin_ctzll(m); APPLYROW((c) * 64 + b); \
                uint64_t above = (b == 63) ? 0ull : (~0ull << (b + 1)); \
                m = (KPC) & ra & above; } } while (0)
        CHUNK(0, kp0); CHUNK(1, kp1); CHUNK(2, kp2); CHUNK(3, kp3);
        CHUNK(4, kp4); CHUNK(5, kp5); CHUNK(6, kp6); CHUNK(7, kp7);
        keepw[0] = kp0; keepw[1] = kp1; keepw[2] = kp2; keepw[3] = kp3;
        keepw[4] = kp4; keepw[5] = kp5; keepw[6] = kp6; keepw[7] = kp7;
        #undef CHUNK
        #undef APPLYROW
        #undef RA64
        #undef VA64
    }
    __syncthreads();

    // ---- epilogue: [512,5], boxes /2048 (exact pow2), zeros if suppressed ----
    if (tid < KTOP) {
        const float inv = 1.0f / 2048.0f;
        int kb = (int)((keepw[tid >> 6] >> (tid & 63)) & 1ull);
        float4 bb = bpk[tid];
        float* o = out + tid * 5;
        if (kb) {
            o[0] = bb.x * inv;
            o[1] = bb.y * inv;
            o[2] = bb.z * inv;
            o[3] = bb.w * inv;
            o[4] = ssc[tid];
        } else {
            o[0] = 0.f; o[1] = 0.f; o[2] = 0.f; o[3] = 0.f; o[4] = 0.f;
        }
    }
}

extern "C" void kernel_launch(void* const* d_in, const int* in_sizes, int n_in,
                              void* d_out, int out_size, void* d_ws, size_t ws_size,
                              hipStream_t stream) {
    const float* loc    = (const float*)d_in[0];   // [1,N,4]
    const float* conf   = (const float*)d_in[1];   // [1,N,2]
    const float* priors = (const float*)d_in[2];   // [N,4]
    float* out = (float*)d_out;                    // [512,5]

    uint8_t* ws = (uint8_t*)d_ws;
    uint32_t* blk_cnt = (uint32_t*)ws;             // 4 KB
    uint64_t* cand    = (uint64_t*)(ws + 4096);    // 2 MB

    // no memset needed: blk_cnt fully written by K1; everything else is LDS
    k1_compact<<<NBLK, 256, 0, stream>>>((const float4*)conf, blk_cnt, cand);
    k2_finish<<<1, 1024, 0, stream>>>((const float4*)loc, (const float4*)priors,
                                      blk_cnt, cand, out);
}